// Round 13
// baseline (228.626 us; speedup 1.0000x reference)
//
#include <hip/hip_runtime.h>
#include <hip/hip_bf16.h>
#include <math.h>

#define B_ 2048
#define D_ 512
#define V_ 100000
#define BM 128
#define BN 128
#define NCT 782           // ceil(100000/128)
#define NBLK (16 * NCT)   // 12512
#define RED_STRIDE 20     // floats; exact 2-way bank aliasing = free

constexpr float S_SCALE = 64.0f;
constexpr float COS_M_ = 0.8775825618903728f;   // cos(0.5)
constexpr float SIN_M_ = 0.479425538604203f;    // sin(0.5)
constexpr float MM_    = 0.2397127693021015f;   // sin(0.5)*0.5
constexpr float THRESH = -0.8775825618903728f;  // cos(pi-0.5)
constexpr float LOG2E  = 1.4426950408889634f;
constexpr float LN2    = 0.6931471805599453f;
constexpr float S2     = 64.0f * LOG2E;          // logits in base-2 domain
constexpr float CMS2   = COS_M_ * S2;            // 81.0537
constexpr float SINM_S2= SIN_M_ * S2;            // 44.2664
constexpr float KS2    = SINM_S2 * SINM_S2;      // (sinm*S2)^2
constexpr float MMS2   = MM_ * S2;               // 22.1335
// Fixed-shift softmax: lg <= 92.33 (base-2); unshifted sum exp2(lg) stays in
// normal f32 range for any input (max 1e5*2^92.3 = 2^109 < 2^128).

typedef __attribute__((ext_vector_type(8))) short short8;
typedef __attribute__((ext_vector_type(4))) float f32x4;
typedef __attribute__((ext_vector_type(8))) int i32x8;

__device__ __forceinline__ unsigned short f2bf(float x) {
    __hip_bfloat16 h = __float2bfloat16(x);
    unsigned short u;
    __builtin_memcpy(&u, &h, 2);
    return u;
}

__device__ __forceinline__ void load_lds16(const void* g, void* l) {
    __builtin_amdgcn_global_load_lds(
        (const __attribute__((address_space(1))) unsigned int*)g,
        (__attribute__((address_space(3))) unsigned int*)l,
        16, 0, 0);
}

// pack 4 floats -> 4 e4m3 bytes (HW RNE/sat via v_cvt_pk_fp8_f32)
__device__ __forceinline__ unsigned int pk_fp8x4(float x, float y, float z, float w) {
    int p = __builtin_amdgcn_cvt_pk_fp8_f32(x, y, 0, false);
    p = __builtin_amdgcn_cvt_pk_fp8_f32(z, w, p, true);
    return (unsigned int)p;
}

// ---------------- K1: normalize embeddings -> bf16 (fallback) + fp8 row-major, rnorm_e ----------------
// Block 0 additionally zeroes the 1KB zbuf used for B-padding staging.
__global__ void k_norm_e(const float* __restrict__ e, unsigned short* __restrict__ ebf,
                         unsigned char* __restrict__ ebf8, float* __restrict__ rne,
                         unsigned int* __restrict__ zbuf) {
    if (zbuf && blockIdx.x == 0) zbuf[threadIdx.x] = 0u;   // 256*4B = 1KB zeros
    int row = blockIdx.x * 4 + (threadIdx.x >> 6);
    int lane = threadIdx.x & 63;
    const float4* src = (const float4*)(e + (size_t)row * D_);
    float4 a = src[lane];
    float4 b = src[lane + 64];
    float ss = a.x*a.x + a.y*a.y + a.z*a.z + a.w*a.w
             + b.x*b.x + b.y*b.y + b.z*b.z + b.w*b.w;
    #pragma unroll
    for (int d = 1; d < 64; d <<= 1) ss += __shfl_xor(ss, d, 64);
    float rn = 1.0f / fmaxf(sqrtf(ss), 1e-12f);
    ushort4* dst = (ushort4*)(ebf + (size_t)row * D_);
    dst[lane]      = make_ushort4(f2bf(a.x*rn), f2bf(a.y*rn), f2bf(a.z*rn), f2bf(a.w*rn));
    dst[lane + 64] = make_ushort4(f2bf(b.x*rn), f2bf(b.y*rn), f2bf(b.z*rn), f2bf(b.w*rn));
    if (ebf8) {
        unsigned int* d8 = (unsigned int*)(ebf8 + (size_t)row * D_);
        d8[lane]      = pk_fp8x4(a.x*rn, a.y*rn, a.z*rn, a.w*rn);
        d8[lane + 64] = pk_fp8x4(b.x*rn, b.y*rn, b.z*rn, b.w*rn);
    }
    if (lane == 0) rne[row] = rn;
}

// ---------------- K2: weight rnorms + normalized fp8 weight (row-major) ----------------
__global__ void k_norm_w(const float* __restrict__ w, float* __restrict__ rnw,
                         unsigned char* __restrict__ wbf8) {
    int row = blockIdx.x * 4 + (threadIdx.x >> 6);
    int lane = threadIdx.x & 63;
    const float4* src = (const float4*)(w + (size_t)row * D_);
    float4 a = src[lane];
    float4 b = src[lane + 64];
    float ss = a.x*a.x + a.y*a.y + a.z*a.z + a.w*a.w
             + b.x*b.x + b.y*b.y + b.z*b.z + b.w*b.w;
    #pragma unroll
    for (int d = 1; d < 64; d <<= 1) ss += __shfl_xor(ss, d, 64);
    float rn = 1.0f / fmaxf(sqrtf(ss), 1e-12f);
    if (wbf8) {
        unsigned int* d8 = (unsigned int*)(wbf8 + (size_t)row * D_);
        d8[lane]      = pk_fp8x4(a.x*rn, a.y*rn, a.z*rn, a.w*rn);
        d8[lane + 64] = pk_fp8x4(b.x*rn, b.y*rn, b.z*rn, b.w*rn);
    }
    if (lane == 0) rnw[row] = rn;
}

// ---------------- K3 (main): MX-fp8 K=128 GEMM + ArcFace + per-tile sum-exp2 ----------------
// mfma_scale_f32_16x16x128_f8f6f4 with unit scales (E8M0 0x7F = 1.0) -> 2x fp8 rate,
// bit-identical e4m3 math. BK=128 ([128][128]B tiles), 2 LDS bufs (64KB, 2 blocks/CU),
// 4 K-steps, vmcnt(0)+barrier per step (steps are long enough to hide HBM latency).
// Per-lane frag = 32 contiguous k-bytes (row=lane&15, k=(lane>>4)*32+[0,32)) -> two
// ds_read_b128 at 16B slots; swizzle slot = chunk ^ (r&7) spreads each wave-read
// evenly (8 accesses/bank = the 1024B floor, 0 conflicts). Source pre-swizzled,
// linear global_load_lds dest (rule #21). C/D layout identical to 16x16x32 -> r9
// epilogue unchanged; OOB B-rows staged as zeros (zbuf), corrected in k_row.
__global__ __launch_bounds__(256, 2) void k_gemm8(const unsigned char* __restrict__ ebf8,
                                                  const unsigned char* __restrict__ wbf8,
                                                  const unsigned char* __restrict__ zbuf,
                                                  float* __restrict__ partials) {
    // XCD-contiguous: XCD x owns wi in [x*1564,(x+1)*1564); 16 rt per ct share B-panel
    const int id = blockIdx.x;
    const int wi = (id & 7) * (NBLK / 8) + (id >> 3);
    const int ct = wi >> 4, rt = wi & 15;
    const int row0 = rt * BM, n0 = ct * BN;
    const int tid = threadIdx.x, lane = tid & 63, wid = tid >> 6;
    const int wm = wid >> 1, wn = wid & 1;

    __shared__ __align__(16) unsigned char lds8[2][32768]; // per buf: A[0,16384) B[16384,32768), [128][128]B each
    float* red = (float*)&lds8[0][0];   // UNION after K-loop: 20480 B < 65536 B

    f32x4 acc[4][4];
    #pragma unroll
    for (int i = 0; i < 4; ++i)
        #pragma unroll
        for (int j = 0; j < 4; ++j)
            acc[i][j] = (f32x4){0.f, 0.f, 0.f, 0.f};

    // ---- staging coords (constant across K-steps) ----
    // Per operand, instr i of wave w stages rows [i*32+w*8, +8): LDS byte
    // p = i*4096 + w*1024 + lane*16 -> row r = i*32+w*8+(lane>>3), phys slot lane&7;
    // logical chunk c_ = (lane&7) ^ (r&7) = (lane&7) ^ ((lane>>3)&7).
    const int c_ = (lane & 7) ^ ((lane >> 3) & 7);
    const unsigned char* pA[4];
    const unsigned char* pB[4];
    #pragma unroll
    for (int i = 0; i < 4; ++i) {
        int r = i * 32 + wid * 8 + (lane >> 3);
        pA[i] = ebf8 + (size_t)(row0 + r) * D_ + c_ * 16;
        int gb = n0 + r;
        // OOB rows stage from the zeroed buffer -> c == 0 logits, corrected in k_row
        pB[i] = (gb < V_) ? wbf8 + (size_t)gb * D_ + c_ * 16 : zbuf + c_ * 16;
    }
    const int lbw = wid * 1024;   // wave-uniform byte offset

    auto STAGE = [&](int t) {
        unsigned char* Lb = &lds8[t & 1][0];
        const int off = t * 128;   // k-tile byte offset (zbuf: reads zeros, off+c_*16 < 1KB)
        #pragma unroll
        for (int i = 0; i < 4; ++i) {
            load_lds16(pA[i] + off, Lb + i * 4096 + lbw);
            load_lds16(pB[i] + off, Lb + 16384 + i * 4096 + lbw);
        }
    };

    // ---- ds_read_b128 byte offsets: slot0 = (2*(lane>>4)) ^ (r&7), r&7 == lane&7 ----
    const int s0 = (((lane >> 4) << 1) ^ (lane & 7)) & 7;
    int aoff[4], boff[4];
    #pragma unroll
    for (int mf = 0; mf < 4; ++mf)
        aoff[mf] = (wm * 64 + mf * 16 + (lane & 15)) * 128 + s0 * 16;
    #pragma unroll
    for (int nf = 0; nf < 4; ++nf)
        boff[nf] = 16384 + (wn * 64 + nf * 16 + (lane & 15)) * 128 + s0 * 16;

    STAGE(0);
    for (int t = 0; t < 4; ++t) {
        // own t-loads (issued at t-1) done; all waves past reads of buf[(t+1)&1]
        asm volatile("s_waitcnt vmcnt(0)\n\ts_barrier" ::: "memory");
        if (t < 3) STAGE(t + 1);

        const char* Lb = (const char*)&lds8[t & 1][0];
        i32x8 a8[4], b8[4];
        #pragma unroll
        for (int mf = 0; mf < 4; ++mf) {
            union { i32x8 v; uint4 q[2]; } fa;
            fa.q[0] = *(const uint4*)(Lb + aoff[mf]);          // chunk 2g   (k lo 16B)
            fa.q[1] = *(const uint4*)(Lb + (aoff[mf] ^ 16));   // chunk 2g+1 (k hi 16B)
            a8[mf] = fa.v;
        }
        #pragma unroll
        for (int nf = 0; nf < 4; ++nf) {
            union { i32x8 v; uint4 q[2]; } fb;
            fb.q[0] = *(const uint4*)(Lb + boff[nf]);
            fb.q[1] = *(const uint4*)(Lb + (boff[nf] ^ 16));
            b8[nf] = fb.v;
        }
        #pragma unroll
        for (int mf = 0; mf < 4; ++mf)
            #pragma unroll
            for (int nf = 0; nf < 4; ++nf)
                acc[mf][nf] = __builtin_amdgcn_mfma_scale_f32_16x16x128_f8f6f4(
                    a8[mf], b8[nf], acc[mf][nf],
                    0, 0,                 // cbsz=fp8(e4m3), blgp=fp8(e4m3)
                    0, 0x7F7F7F7F,        // scale A: byte sel 0, E8M0 1.0
                    0, 0x7F7F7F7F);       // scale B: byte sel 0, E8M0 1.0
    }
    __syncthreads();   // K-loop LDS reads done before epilogue overwrites the buffers

    // ---- epilogue: trimmed ArcFace transform, 8 VALU + 2 trans per logit ----
    #pragma unroll
    for (int mf = 0; mf < 4; ++mf) {
        #pragma unroll
        for (int r = 0; r < 4; ++r) {
            float vsum = 0.0f;
            #pragma unroll
            for (int nf = 0; nf < 4; ++nf) {
                float c = acc[mf][nf][r];
                c = __builtin_amdgcn_fmed3f(c, -1.0f, 1.0f);      // clamp
                float tt = fmaf(-c, c, 1.0f);                      // >= 0 after clamp
                float sts = __builtin_amdgcn_sqrtf(tt * KS2);      // sin(th)*sinm*S2
                float lgm = fmaf(c, CMS2, -sts);
                float lga = fmaf(c, S2, -MMS2);
                float lg = (c > THRESH) ? lgm : lga;
                vsum += __builtin_amdgcn_exp2f(lg);
            }
            int rowloc = wm * 64 + mf * 16 + (lane >> 4) * 4 + r;
            red[(wn * BM + rowloc) * RED_STRIDE + (lane & 15)] = vsum;
        }
    }
    __syncthreads();
    if (tid < BM) {
        const float4* p0 = (const float4*)(red + (size_t)tid * RED_STRIDE);
        const float4* p1 = (const float4*)(red + (size_t)(BM + tid) * RED_STRIDE);
        float s = 0.0f;
        #pragma unroll
        for (int q = 0; q < 4; ++q) {
            float4 u = p0[q], v = p1[q];
            s += (u.x + u.y) + (u.z + u.w) + (v.x + v.y) + (v.z + v.w);
        }
        partials[(size_t)ct * B_ + row0 + tid] = s;   // ct-major: coalesced store
    }
}

// ---------------- fallback GEMM (no workspace): round-5 proven bf16 path ----------------
__device__ __forceinline__ int swz64(int row, int col) {   // [128][64] ushort tile
    return (row * 64 + col) ^ ((row & 7) << 3);
}
__global__ __launch_bounds__(256) void k_gemm_fb(const unsigned short* __restrict__ ebf,
                                                 const float* __restrict__ w,
                                                 const float* __restrict__ rnw,
                                                 float* __restrict__ partials) {
    const int rt = blockIdx.x, ct = blockIdx.y;
    const int row0 = rt * BM, n0 = ct * BN;
    const int tid = threadIdx.x, lane = tid & 63, wid = tid >> 6;
    const int wm = wid >> 1, wn = wid & 1;
    __shared__ __align__(16) unsigned short As[BM * 64];
    __shared__ __align__(16) unsigned short Bs[BN * 64];
    float* red = (float*)&As[0];
    f32x4 acc[4][4];
    #pragma unroll
    for (int i = 0; i < 4; ++i)
        #pragma unroll
        for (int j = 0; j < 4; ++j) acc[i][j] = (f32x4){0.f, 0.f, 0.f, 0.f};
    for (int ks = 0; ks < D_ / 64; ++ks) {
        const int kk = ks * 64;
        #pragma unroll
        for (int p = 0; p < 4; ++p) {
            int idx = p * 256 + tid;
            int r = idx >> 3, c = (idx & 7) * 8;
            *(uint4*)(As + swz64(r, c)) = *(const uint4*)(ebf + (size_t)(row0 + r) * D_ + kk + c);
        }
        #pragma unroll
        for (int p = 0; p < 4; ++p) {
            int idx = p * 256 + tid;
            int r = idx >> 3, c = (idx & 7) * 8;
            int gr = n0 + r;
            uint4 val = make_uint4(0, 0, 0, 0);
            if (gr < V_) {
                float rn = rnw[gr];
                const float4* src = (const float4*)(w + (size_t)gr * D_ + kk + c);
                float4 f0 = src[0], f1 = src[1];
                val.x = (unsigned)f2bf(f0.x*rn) | ((unsigned)f2bf(f0.y*rn) << 16);
                val.y = (unsigned)f2bf(f0.z*rn) | ((unsigned)f2bf(f0.w*rn) << 16);
                val.z = (unsigned)f2bf(f1.x*rn) | ((unsigned)f2bf(f1.y*rn) << 16);
                val.w = (unsigned)f2bf(f1.z*rn) | ((unsigned)f2bf(f1.w*rn) << 16);
            }
            *(uint4*)(Bs + swz64(r, c)) = val;
        }
        __syncthreads();
        #pragma unroll
        for (int kc = 0; kc < 2; ++kc) {
            const int kbase = kc * 32 + (lane >> 4) * 8;
            short8 af[4], bfr[4];
            #pragma unroll
            for (int mf = 0; mf < 4; ++mf) af[mf] = *(const short8*)(As + swz64(wm * 64 + mf * 16 + (lane & 15), kbase));
            #pragma unroll
            for (int nf = 0; nf < 4; ++nf) bfr[nf] = *(const short8*)(Bs + swz64(wn * 64 + nf * 16 + (lane & 15), kbase));
            #pragma unroll
            for (int mf = 0; mf < 4; ++mf)
                #pragma unroll
                for (int nf = 0; nf < 4; ++nf)
                    acc[mf][nf] = __builtin_amdgcn_mfma_f32_16x16x32_bf16(af[mf], bfr[nf], acc[mf][nf], 0, 0, 0);
        }
        __syncthreads();
    }
    const int vlim = V_ - n0;
    #pragma unroll
    for (int mf = 0; mf < 4; ++mf) {
        #pragma unroll
        for (int r = 0; r < 4; ++r) {
            float vsum = 0.0f;
            #pragma unroll
            for (int nf = 0; nf < 4; ++nf) {
                float c = acc[mf][nf][r];
                int coltile = wn * 64 + nf * 16 + (lane & 15);
                c = __builtin_amdgcn_fmed3f(c, -1.0f, 1.0f);
                float tt = fmaf(-c, c, 1.0f);
                float sts = __builtin_amdgcn_sqrtf(tt * KS2);
                float lgm = fmaf(c, CMS2, -sts);
                float lga = fmaf(c, S2, -MMS2);
                float lg = (c > THRESH) ? lgm : lga;
                lg = (coltile < vlim) ? lg : -INFINITY;
                vsum += __builtin_amdgcn_exp2f(lg);
            }
            int rowloc = wm * 64 + mf * 16 + (lane >> 4) * 4 + r;
            red[(wn * BM + rowloc) * RED_STRIDE + (lane & 15)] = vsum;
        }
    }
    __syncthreads();
    if (tid < BM) {
        const float4* p0 = (const float4*)(red + (size_t)tid * RED_STRIDE);
        const float4* p1 = (const float4*)(red + (size_t)(BM + tid) * RED_STRIDE);
        float s = 0.0f;
        #pragma unroll
        for (int q = 0; q < 4; ++q) {
            float4 u = p0[q], v = p1[q];
            s += (u.x + u.y) + (u.z + u.w) + (v.x + v.y) + (v.z + v.w);
        }
        partials[(size_t)ct * B_ + row0 + tid] = s;
    }
}

// label dtype robustness: harness may hand int32 or int64 (LE).
__device__ __forceinline__ int get_label(const int* lab32, int b) {
    bool is64 = true;
    #pragma unroll
    for (int i = 1; i < 16; i += 2) is64 = is64 && (lab32[i] == 0);
    return is64 ? (int)(((const long long*)lab32)[b]) : lab32[b];
}

// ---------------- K4: per-row sum of partials (minus pad correction) + exact label logit ----------------
__global__ void k_row(const float* __restrict__ e, const float* __restrict__ w,
                      const int* __restrict__ labels, const float* __restrict__ rne,
                      const float* __restrict__ rnw, const float* __restrict__ partials,
                      float* __restrict__ row_nll, float padcorr) {
    const int b = blockIdx.x;
    const int tid = threadIdx.x;

    float s = 0.0f;
    for (int ctn = tid; ctn < NCT; ctn += 256) s += partials[(size_t)ctn * B_ + b];
    #pragma unroll
    for (int d = 1; d < 64; d <<= 1) s += __shfl_xor(s, d, 64);
    __shared__ float ss_[4], sd_[4];
    if ((tid & 63) == 0) ss_[tid >> 6] = s;

    int lab = get_label(labels, b);
    const float* ep = e + (size_t)b * D_;
    const float* wp = w + (size_t)lab * D_;
    float dot = ep[tid] * wp[tid] + ep[tid + 256] * wp[tid + 256];
    #pragma unroll
    for (int d = 1; d < 64; d <<= 1) dot += __shfl_xor(dot, d, 64);
    if ((tid & 63) == 0) sd_[tid >> 6] = dot;
    __syncthreads();

    if (tid == 0) {
        float S = (ss_[0] + ss_[1]) + (ss_[2] + ss_[3]) - padcorr;  // remove zero-pad cols
        float lse = __builtin_amdgcn_logf(S) * LN2;   // v_log_f32 = log2; fixed shift M0=0
        float c = (sd_[0] + sd_[1] + sd_[2] + sd_[3]) * rne[b] * rnw[lab];
        c = fminf(fmaxf(c, -1.0f), 1.0f);
        float st = sqrtf(fmaxf(1.0f - c * c, 0.0f));
        float cm = c * COS_M_ - st * SIN_M_;
        cm = (c > THRESH) ? cm : (c - MM_);
        row_nll[b] = lse - cm * S_SCALE;
    }
}

// ---------------- K5: mean ----------------
__global__ void k_mean(const float* __restrict__ row_nll, float* __restrict__ out) {
    int tid = threadIdx.x;
    float s = 0.0f;
    for (int i = tid; i < B_; i += 256) s += row_nll[i];
    #pragma unroll
    for (int d = 1; d < 64; d <<= 1) s += __shfl_xor(s, d, 64);
    __shared__ float sb[4];
    if ((tid & 63) == 0) sb[tid >> 6] = s;
    __syncthreads();
    if (tid == 0) out[0] = (sb[0] + sb[1] + sb[2] + sb[3]) / (float)B_;
}

extern "C" void kernel_launch(void* const* d_in, const int* in_sizes, int n_in,
                              void* d_out, int out_size, void* d_ws, size_t ws_size,
                              hipStream_t stream) {
    const float* e      = (const float*)d_in[0];
    const int*   labels = (const int*)d_in[1];
    const float* w      = (const float*)d_in[2];
    float* out = (float*)d_out;
    char* ws = (char*)d_ws;

    unsigned short* ebf = (unsigned short*)ws;                   // 2,097,152 B
    float* rne          = (float*)(ws + 2097152);                // 8,192 B
    float* rnw          = (float*)(ws + 2105344);                // 400,000 B
    float* partials     = (float*)(ws + 2505344);                // 6,406,144 B (NCT*B_*4)
    float* row_nll      = (float*)(ws + 8911488);                // 8,192 B
    unsigned int* zbuf  = (unsigned int*)(ws + 8919680);         // 4,096 B zero staging
    unsigned char* ebf8 = (unsigned char*)(ws + 8923776);        // 1,048,576 B
    unsigned char* wbf8 = (unsigned char*)(ws + 9972352);        // 51,200,000 B
    const size_t NEED_PRE = 9972352 + (size_t)V_ * D_;

    const bool pre = ws_size >= NEED_PRE;
    // exact correction: 96 padding cols, each contributing exp2(-sinm*S2) (c = 0)
    const float padcorr = pre ? 96.0f * exp2f(-(float)SINM_S2) : 0.0f;

    k_norm_e<<<B_ / 4, 256, 0, stream>>>(e, ebf, pre ? ebf8 : nullptr, rne, pre ? zbuf : nullptr);
    k_norm_w<<<V_ / 4, 256, 0, stream>>>(w, rnw, pre ? wbf8 : nullptr);
    if (pre) {
        k_gemm8<<<NBLK, 256, 0, stream>>>(ebf8, wbf8, (const unsigned char*)zbuf, partials);
    } else {
        dim3 g3(B_ / BM, NCT);
        k_gemm_fb<<<g3, 256, 0, stream>>>(ebf, w, rnw, partials);
    }
    k_row<<<B_, 256, 0, stream>>>(e, w, labels, rne, rnw, partials, row_nll, padcorr);
    k_mean<<<1, 256, 0, stream>>>(row_nll, out);
}

// Round 14
// 200.318 us; speedup vs baseline: 1.1413x; 1.1413x over previous
//
#include <hip/hip_runtime.h>
#include <hip/hip_bf16.h>
#include <math.h>

#define B_ 2048
#define D_ 512
#define V_ 100000
#define BM 128
#define BN 128
#define NCT 782           // ceil(100000/128)
#define NBLK (16 * NCT)   // 12512
#define NBUF 3
#define RED_STRIDE 20     // floats (fallback epilogue)
#define RSTR2 36          // floats, 32x32 epilogue; 16B-aligned rows

constexpr float S_SCALE = 64.0f;
constexpr float COS_M_ = 0.8775825618903728f;   // cos(0.5)
constexpr float SIN_M_ = 0.479425538604203f;    // sin(0.5)
constexpr float MM_    = 0.2397127693021015f;   // sin(0.5)*0.5
constexpr float THRESH = -0.8775825618903728f;  // cos(pi-0.5)
constexpr float LOG2E  = 1.4426950408889634f;
constexpr float LN2    = 0.6931471805599453f;
constexpr float S2     = 64.0f * LOG2E;          // logits in base-2 domain
constexpr float CMS2   = COS_M_ * S2;            // 81.0537
constexpr float SINM_S2= SIN_M_ * S2;            // 44.2664
constexpr float KS2    = SINM_S2 * SINM_S2;      // (sinm*S2)^2
constexpr float MMS2   = MM_ * S2;               // 22.1335
// Fixed-shift softmax: lg <= 92.33 (base-2); unshifted sum exp2(lg) stays in
// normal f32 range for any input (max 1e5*2^92.3 = 2^109 < 2^128).

typedef __attribute__((ext_vector_type(8))) short short8;
typedef __attribute__((ext_vector_type(4))) float f32x4;
typedef __attribute__((ext_vector_type(16))) float f32x16;
typedef __attribute__((ext_vector_type(8))) int i32x8;

__device__ __forceinline__ unsigned short f2bf(float x) {
    __hip_bfloat16 h = __float2bfloat16(x);
    unsigned short u;
    __builtin_memcpy(&u, &h, 2);
    return u;
}

__device__ __forceinline__ void load_lds16(const void* g, void* l) {
    __builtin_amdgcn_global_load_lds(
        (const __attribute__((address_space(1))) unsigned int*)g,
        (__attribute__((address_space(3))) unsigned int*)l,
        16, 0, 0);
}

// pack 4 floats -> 4 e4m3 bytes (HW RNE/sat via v_cvt_pk_fp8_f32)
__device__ __forceinline__ unsigned int pk_fp8x4(float x, float y, float z, float w) {
    int p = __builtin_amdgcn_cvt_pk_fp8_f32(x, y, 0, false);
    p = __builtin_amdgcn_cvt_pk_fp8_f32(z, w, p, true);
    return (unsigned int)p;
}

// ---------------- K1: normalize embeddings -> bf16 (fallback) + fp8 row-major, rnorm_e ----------------
// Block 0 additionally zeroes the 1KB zbuf used for B-padding staging.
__global__ void k_norm_e(const float* __restrict__ e, unsigned short* __restrict__ ebf,
                         unsigned char* __restrict__ ebf8, float* __restrict__ rne,
                         unsigned int* __restrict__ zbuf) {
    if (zbuf && blockIdx.x == 0) zbuf[threadIdx.x] = 0u;   // 256*4B = 1KB zeros
    int row = blockIdx.x * 4 + (threadIdx.x >> 6);
    int lane = threadIdx.x & 63;
    const float4* src = (const float4*)(e + (size_t)row * D_);
    float4 a = src[lane];
    float4 b = src[lane + 64];
    float ss = a.x*a.x + a.y*a.y + a.z*a.z + a.w*a.w
             + b.x*b.x + b.y*b.y + b.z*b.z + b.w*b.w;
    #pragma unroll
    for (int d = 1; d < 64; d <<= 1) ss += __shfl_xor(ss, d, 64);
    float rn = 1.0f / fmaxf(sqrtf(ss), 1e-12f);
    ushort4* dst = (ushort4*)(ebf + (size_t)row * D_);
    dst[lane]      = make_ushort4(f2bf(a.x*rn), f2bf(a.y*rn), f2bf(a.z*rn), f2bf(a.w*rn));
    dst[lane + 64] = make_ushort4(f2bf(b.x*rn), f2bf(b.y*rn), f2bf(b.z*rn), f2bf(b.w*rn));
    if (ebf8) {
        unsigned int* d8 = (unsigned int*)(ebf8 + (size_t)row * D_);
        d8[lane]      = pk_fp8x4(a.x*rn, a.y*rn, a.z*rn, a.w*rn);
        d8[lane + 64] = pk_fp8x4(b.x*rn, b.y*rn, b.z*rn, b.w*rn);
    }
    if (lane == 0) rne[row] = rn;
}

// ---------------- K2: weight rnorms + normalized fp8 weight (row-major) ----------------
__global__ void k_norm_w(const float* __restrict__ w, float* __restrict__ rnw,
                         unsigned char* __restrict__ wbf8) {
    int row = blockIdx.x * 4 + (threadIdx.x >> 6);
    int lane = threadIdx.x & 63;
    const float4* src = (const float4*)(w + (size_t)row * D_);
    float4 a = src[lane];
    float4 b = src[lane + 64];
    float ss = a.x*a.x + a.y*a.y + a.z*a.z + a.w*a.w
             + b.x*b.x + b.y*b.y + b.z*b.z + b.w*b.w;
    #pragma unroll
    for (int d = 1; d < 64; d <<= 1) ss += __shfl_xor(ss, d, 64);
    float rn = 1.0f / fmaxf(sqrtf(ss), 1e-12f);
    if (wbf8) {
        unsigned int* d8 = (unsigned int*)(wbf8 + (size_t)row * D_);
        d8[lane]      = pk_fp8x4(a.x*rn, a.y*rn, a.z*rn, a.w*rn);
        d8[lane + 64] = pk_fp8x4(b.x*rn, b.y*rn, b.z*rn, b.w*rn);
    }
    if (lane == 0) rnw[row] = rn;
}

// ---------------- K3 (main): MX-fp8 32x32x64 GEMM + ArcFace + per-tile sum-exp2 ----------------
// mfma_scale_f32_32x32x64_f8f6f4, unit scales (E8M0 0x7F = 1.0) -> 2x fp8 rate,
// bit-identical e4m3 math (r13 proved the MX path numerically, absmax 0).
// Geometry reverted to the r12-PROVEN 0-conflict layout: [128][64]B tiles, BK=64,
// 3 LDS bufs (48KB, 3 blocks/CU), 8 K-steps, 1 s_barrier/step, counted vmcnt(4),
// slot = chunk ^ ((r>>1)&3) 16B swizzle, pre-swizzled source, linear gload_lds dest.
// Per-lane frag: row = lane&31, k = (lane>>5)*32+[0,32) -> two ds_read_b128 at
// adjacent slots (off, off^16); lanes 0-7 cover all 32 banks once (r12-verified walk).
__global__ __launch_bounds__(256, 3) void k_gemm8(const unsigned char* __restrict__ ebf8,
                                                  const unsigned char* __restrict__ wbf8,
                                                  const unsigned char* __restrict__ zbuf,
                                                  float* __restrict__ partials) {
    // XCD-contiguous: XCD x owns wi in [x*1564,(x+1)*1564); 16 rt per ct share B-panel
    const int id = blockIdx.x;
    const int wi = (id & 7) * (NBLK / 8) + (id >> 3);
    const int ct = wi >> 4, rt = wi & 15;
    const int row0 = rt * BM, n0 = ct * BN;
    const int tid = threadIdx.x, lane = tid & 63, wid = tid >> 6;
    const int wm = wid >> 1, wn = wid & 1;

    __shared__ __align__(16) unsigned char lds8[NBUF][16384]; // per buf: A[0,8192) B[8192,16384), [128][64]B each
    float* red = (float*)&lds8[0][0];   // UNION after K-loop: 2*128*RSTR2*4 = 36,864B < 49,152B

    f32x16 acc[2][2];
    #pragma unroll
    for (int i = 0; i < 2; ++i)
        #pragma unroll
        for (int j = 0; j < 2; ++j)
            #pragma unroll
            for (int q = 0; q < 16; ++q) acc[i][j][q] = 0.0f;

    // ---- staging coords (r12-identical): wave w instr i covers rows i*64+w*16+(lane>>2),
    // phys slot lane&3, logical chunk c_ = (lane&3) ^ ((r>>1)&3) = (lane&3)^((lane>>3)&3)
    const int c_ = (lane & 3) ^ ((lane >> 3) & 3);
    const int r0s = wid * 16 + (lane >> 2);
    const unsigned char* gA0 = ebf8 + (size_t)(row0 + r0s) * D_ + c_ * 16;
    const unsigned char* gA1 = ebf8 + (size_t)(row0 + 64 + r0s) * D_ + c_ * 16;
    int gb0 = n0 + r0s, gb1 = n0 + 64 + r0s;
    // OOB rows stage from the zeroed buffer -> c == 0 logits, corrected in k_row
    const unsigned char* gB0 = (gb0 < V_) ? wbf8 + (size_t)gb0 * D_ + c_ * 16 : zbuf + c_ * 16;
    const unsigned char* gB1 = (gb1 < V_) ? wbf8 + (size_t)gb1 * D_ + c_ * 16 : zbuf + c_ * 16;
    const int lb = wid * 1024;   // wave-uniform byte offset

    auto STAGE = [&](int t) {
        unsigned char* Lb = &lds8[t % NBUF][0];
        const int off = t * 64;   // BK=64 bytes per k-step (zbuf: off+c_*16 <= 448+48+16 < 1KB)
        load_lds16(gA0 + off, Lb + lb);
        load_lds16(gA1 + off, Lb + 4096 + lb);
        load_lds16(gB0 + off, Lb + 8192 + lb);
        load_lds16(gB1 + off, Lb + 12288 + lb);
    };

    // ---- ds_read_b128 offsets: slot1 = (2*(lane>>5)) ^ ((r>>1)&3), r = base + (lane&31)
    // -> (r>>1)&3 == (lane>>1)&3 (base multiple of 32). Partner slot = slot1^1 (byte ^16).
    const int s1 = ((lane >> 5) << 1) ^ ((lane >> 1) & 3);
    int aoff[2], boff[2];
    #pragma unroll
    for (int mi = 0; mi < 2; ++mi)
        aoff[mi] = (wm * 64 + mi * 32 + (lane & 31)) * 64 + s1 * 16;
    #pragma unroll
    for (int ni = 0; ni < 2; ++ni)
        boff[ni] = 8192 + (wn * 64 + ni * 32 + (lane & 31)) * 64 + s1 * 16;

    STAGE(0);
    STAGE(1);
    for (int t = 0; t < 8; ++t) {
        // own t-loads (issued at t-2) done; t+1's 4 stay in flight; then block-sync.
        if (t < 7) asm volatile("s_waitcnt vmcnt(4)\n\ts_barrier" ::: "memory");
        else       asm volatile("s_waitcnt vmcnt(0)\n\ts_barrier" ::: "memory");
        if (t + 2 < 8) STAGE(t + 2);   // buf[(t+2)%3] last read at t-1, barrier-ordered safe

        const char* Lb = (const char*)&lds8[t % NBUF][0];
        i32x8 a8[2], b8[2];
        #pragma unroll
        for (int mi = 0; mi < 2; ++mi) {
            union { i32x8 v; uint4 q[2]; } fa;
            fa.q[0] = *(const uint4*)(Lb + aoff[mi]);          // k lo 16B (chunk 2g)
            fa.q[1] = *(const uint4*)(Lb + (aoff[mi] ^ 16));   // k hi 16B (chunk 2g+1)
            a8[mi] = fa.v;
        }
        #pragma unroll
        for (int ni = 0; ni < 2; ++ni) {
            union { i32x8 v; uint4 q[2]; } fb;
            fb.q[0] = *(const uint4*)(Lb + boff[ni]);
            fb.q[1] = *(const uint4*)(Lb + (boff[ni] ^ 16));
            b8[ni] = fb.v;
        }
        #pragma unroll
        for (int mi = 0; mi < 2; ++mi)
            #pragma unroll
            for (int ni = 0; ni < 2; ++ni)
                acc[mi][ni] = __builtin_amdgcn_mfma_scale_f32_32x32x64_f8f6f4(
                    a8[mi], b8[ni], acc[mi][ni],
                    0, 0,                 // cbsz=fp8(e4m3), blgp=fp8(e4m3)
                    0, 0x7F7F7F7F,        // scale A: byte sel 0, E8M0 1.0
                    0, 0x7F7F7F7F);       // scale B: byte sel 0, E8M0 1.0
    }
    __syncthreads();   // K-loop LDS reads done before epilogue overwrites the buffers

    // ---- epilogue: trimmed ArcFace; 32x32 C layout col=lane&31, row=(rg&3)+8*(rg>>2)+4*(lane>>5)
    const int hi4 = (lane >> 5) * 4;
    #pragma unroll
    for (int mi = 0; mi < 2; ++mi) {
        #pragma unroll
        for (int rg = 0; rg < 16; ++rg) {
            float vsum = 0.0f;
            #pragma unroll
            for (int ni = 0; ni < 2; ++ni) {
                float c = acc[mi][ni][rg];
                c = __builtin_amdgcn_fmed3f(c, -1.0f, 1.0f);      // clamp
                float tt = fmaf(-c, c, 1.0f);                      // >= 0 after clamp
                float sts = __builtin_amdgcn_sqrtf(tt * KS2);      // sin(th)*sinm*S2
                float lgm = fmaf(c, CMS2, -sts);
                float lga = fmaf(c, S2, -MMS2);
                float lg = (c > THRESH) ? lgm : lga;
                vsum += __builtin_amdgcn_exp2f(lg);
            }
            int rowloc = wm * 64 + mi * 32 + (rg & 3) + 8 * (rg >> 2) + hi4;
            red[(wn * BM + rowloc) * RSTR2 + (lane & 31)] = vsum;
        }
    }
    __syncthreads();
    if (tid < BM) {
        float s = 0.0f;
        #pragma unroll
        for (int h = 0; h < 2; ++h) {
            const float4* p = (const float4*)(red + (size_t)(h * BM + tid) * RSTR2);
            #pragma unroll
            for (int q = 0; q < 8; ++q) {
                float4 u = p[q];
                s += (u.x + u.y) + (u.z + u.w);
            }
        }
        partials[(size_t)ct * B_ + row0 + tid] = s;   // ct-major: coalesced store
    }
}

// ---------------- fallback GEMM (no workspace): round-5 proven bf16 path ----------------
__device__ __forceinline__ int swz64(int row, int col) {   // [128][64] ushort tile
    return (row * 64 + col) ^ ((row & 7) << 3);
}
__global__ __launch_bounds__(256) void k_gemm_fb(const unsigned short* __restrict__ ebf,
                                                 const float* __restrict__ w,
                                                 const float* __restrict__ rnw,
                                                 float* __restrict__ partials) {
    const int rt = blockIdx.x, ct = blockIdx.y;
    const int row0 = rt * BM, n0 = ct * BN;
    const int tid = threadIdx.x, lane = tid & 63, wid = tid >> 6;
    const int wm = wid >> 1, wn = wid & 1;
    __shared__ __align__(16) unsigned short As[BM * 64];
    __shared__ __align__(16) unsigned short Bs[BN * 64];
    float* red = (float*)&As[0];
    f32x4 acc[4][4];
    #pragma unroll
    for (int i = 0; i < 4; ++i)
        #pragma unroll
        for (int j = 0; j < 4; ++j) acc[i][j] = (f32x4){0.f, 0.f, 0.f, 0.f};
    for (int ks = 0; ks < D_ / 64; ++ks) {
        const int kk = ks * 64;
        #pragma unroll
        for (int p = 0; p < 4; ++p) {
            int idx = p * 256 + tid;
            int r = idx >> 3, c = (idx & 7) * 8;
            *(uint4*)(As + swz64(r, c)) = *(const uint4*)(ebf + (size_t)(row0 + r) * D_ + kk + c);
        }
        #pragma unroll
        for (int p = 0; p < 4; ++p) {
            int idx = p * 256 + tid;
            int r = idx >> 3, c = (idx & 7) * 8;
            int gr = n0 + r;
            uint4 val = make_uint4(0, 0, 0, 0);
            if (gr < V_) {
                float rn = rnw[gr];
                const float4* src = (const float4*)(w + (size_t)gr * D_ + kk + c);
                float4 f0 = src[0], f1 = src[1];
                val.x = (unsigned)f2bf(f0.x*rn) | ((unsigned)f2bf(f0.y*rn) << 16);
                val.y = (unsigned)f2bf(f0.z*rn) | ((unsigned)f2bf(f0.w*rn) << 16);
                val.z = (unsigned)f2bf(f1.x*rn) | ((unsigned)f2bf(f1.y*rn) << 16);
                val.w = (unsigned)f2bf(f1.z*rn) | ((unsigned)f2bf(f1.w*rn) << 16);
            }
            *(uint4*)(Bs + swz64(r, c)) = val;
        }
        __syncthreads();
        #pragma unroll
        for (int kc = 0; kc < 2; ++kc) {
            const int kbase = kc * 32 + (lane >> 4) * 8;
            short8 af[4], bfr[4];
            #pragma unroll
            for (int mf = 0; mf < 4; ++mf) af[mf] = *(const short8*)(As + swz64(wm * 64 + mf * 16 + (lane & 15), kbase));
            #pragma unroll
            for (int nf = 0; nf < 4; ++nf) bfr[nf] = *(const short8*)(Bs + swz64(wn * 64 + nf * 16 + (lane & 15), kbase));
            #pragma unroll
            for (int mf = 0; mf < 4; ++mf)
                #pragma unroll
                for (int nf = 0; nf < 4; ++nf)
                    acc[mf][nf] = __builtin_amdgcn_mfma_f32_16x16x32_bf16(af[mf], bfr[nf], acc[mf][nf], 0, 0, 0);
        }
        __syncthreads();
    }
    const int vlim = V_ - n0;
    #pragma unroll
    for (int mf = 0; mf < 4; ++mf) {
        #pragma unroll
        for (int r = 0; r < 4; ++r) {
            float vsum = 0.0f;
            #pragma unroll
            for (int nf = 0; nf < 4; ++nf) {
                float c = acc[mf][nf][r];
                int coltile = wn * 64 + nf * 16 + (lane & 15);
                c = __builtin_amdgcn_fmed3f(c, -1.0f, 1.0f);
                float tt = fmaf(-c, c, 1.0f);
                float sts = __builtin_amdgcn_sqrtf(tt * KS2);
                float lgm = fmaf(c, CMS2, -sts);
                float lga = fmaf(c, S2, -MMS2);
                float lg = (c > THRESH) ? lgm : lga;
                lg = (coltile < vlim) ? lg : -INFINITY;
                vsum += __builtin_amdgcn_exp2f(lg);
            }
            int rowloc = wm * 64 + mf * 16 + (lane >> 4) * 4 + r;
            red[(wn * BM + rowloc) * RED_STRIDE + (lane & 15)] = vsum;
        }
    }
    __syncthreads();
    if (tid < BM) {
        const float4* p0 = (const float4*)(red + (size_t)tid * RED_STRIDE);
        const float4* p1 = (const float4*)(red + (size_t)(BM + tid) * RED_STRIDE);
        float s = 0.0f;
        #pragma unroll
        for (int q = 0; q < 4; ++q) {
            float4 u = p0[q], v = p1[q];
            s += (u.x + u.y) + (u.z + u.w) + (v.x + v.y) + (v.z + v.w);
        }
        partials[(size_t)ct * B_ + row0 + tid] = s;
    }
}

// label dtype robustness: harness may hand int32 or int64 (LE).
__device__ __forceinline__ int get_label(const int* lab32, int b) {
    bool is64 = true;
    #pragma unroll
    for (int i = 1; i < 16; i += 2) is64 = is64 && (lab32[i] == 0);
    return is64 ? (int)(((const long long*)lab32)[b]) : lab32[b];
}

// ---------------- K4: per-row sum of partials (minus pad correction) + exact label logit ----------------
__global__ void k_row(const float* __restrict__ e, const float* __restrict__ w,
                      const int* __restrict__ labels, const float* __restrict__ rne,
                      const float* __restrict__ rnw, const float* __restrict__ partials,
                      float* __restrict__ row_nll, float padcorr) {
    const int b = blockIdx.x;
    const int tid = threadIdx.x;

    float s = 0.0f;
    for (int ctn = tid; ctn < NCT; ctn += 256) s += partials[(size_t)ctn * B_ + b];
    #pragma unroll
    for (int d = 1; d < 64; d <<= 1) s += __shfl_xor(s, d, 64);
    __shared__ float ss_[4], sd_[4];
    if ((tid & 63) == 0) ss_[tid >> 6] = s;

    int lab = get_label(labels, b);
    const float* ep = e + (size_t)b * D_;
    const float* wp = w + (size_t)lab * D_;
    float dot = ep[tid] * wp[tid] + ep[tid + 256] * wp[tid + 256];
    #pragma unroll
    for (int d = 1; d < 64; d <<= 1) dot += __shfl_xor(dot, d, 64);
    if ((tid & 63) == 0) sd_[tid >> 6] = dot;
    __syncthreads();

    if (tid == 0) {
        float S = (ss_[0] + ss_[1]) + (ss_[2] + ss_[3]) - padcorr;  // remove zero-pad cols
        float lse = __builtin_amdgcn_logf(S) * LN2;   // v_log_f32 = log2; fixed shift M0=0
        float c = (sd_[0] + sd_[1] + sd_[2] + sd_[3]) * rne[b] * rnw[lab];
        c = fminf(fmaxf(c, -1.0f), 1.0f);
        float st = sqrtf(fmaxf(1.0f - c * c, 0.0f));
        float cm = c * COS_M_ - st * SIN_M_;
        cm = (c > THRESH) ? cm : (c - MM_);
        row_nll[b] = lse - cm * S_SCALE;
    }
}

// ---------------- K5: mean ----------------
__global__ void k_mean(const float* __restrict__ row_nll, float* __restrict__ out) {
    int tid = threadIdx.x;
    float s = 0.0f;
    for (int i = tid; i < B_; i += 256) s += row_nll[i];
    #pragma unroll
    for (int d = 1; d < 64; d <<= 1) s += __shfl_xor(s, d, 64);
    __shared__ float sb[4];
    if ((tid & 63) == 0) sb[tid >> 6] = s;
    __syncthreads();
    if (tid == 0) out[0] = (sb[0] + sb[1] + sb[2] + sb[3]) / (float)B_;
}

extern "C" void kernel_launch(void* const* d_in, const int* in_sizes, int n_in,
                              void* d_out, int out_size, void* d_ws, size_t ws_size,
                              hipStream_t stream) {
    const float* e      = (const float*)d_in[0];
    const int*   labels = (const int*)d_in[1];
    const float* w      = (const float*)d_in[2];
    float* out = (float*)d_out;
    char* ws = (char*)d_ws;

    unsigned short* ebf = (unsigned short*)ws;                   // 2,097,152 B
    float* rne          = (float*)(ws + 2097152);                // 8,192 B
    float* rnw          = (float*)(ws + 2105344);                // 400,000 B
    float* partials     = (float*)(ws + 2505344);                // 6,406,144 B (NCT*B_*4)
    float* row_nll      = (float*)(ws + 8911488);                // 8,192 B
    unsigned int* zbuf  = (unsigned int*)(ws + 8919680);         // 4,096 B zero staging
    unsigned char* ebf8 = (unsigned char*)(ws + 8923776);        // 1,048,576 B
    unsigned char* wbf8 = (unsigned char*)(ws + 9972352);        // 51,200,000 B
    const size_t NEED_PRE = 9972352 + (size_t)V_ * D_;

    const bool pre = ws_size >= NEED_PRE;
    // exact correction: 96 padding cols, each contributing exp2(-sinm*S2) (c = 0)
    const float padcorr = pre ? 96.0f * exp2f(-(float)SINM_S2) : 0.0f;

    k_norm_e<<<B_ / 4, 256, 0, stream>>>(e, ebf, pre ? ebf8 : nullptr, rne, pre ? zbuf : nullptr);
    k_norm_w<<<V_ / 4, 256, 0, stream>>>(w, rnw, pre ? wbf8 : nullptr);
    if (pre) {
        k_gemm8<<<NBLK, 256, 0, stream>>>(ebf8, wbf8, (const unsigned char*)zbuf, partials);
    } else {
        dim3 g3(B_ / BM, NCT);
        k_gemm_fb<<<g3, 256, 0, stream>>>(ebf, w, rnw, partials);
    }
    k_row<<<B_, 256, 0, stream>>>(e, w, labels, rne, rnw, partials, row_nll, padcorr);
    k_mean<<<1, 256, 0, stream>>>(row_nll, out);
}